// Round 4
// baseline (230.995 us; speedup 1.0000x reference)
//
#include <hip/hip_runtime.h>
#include <hip/hip_fp16.h>

#define TT    64        // output tokens per block
#define HALO  9         // (KERNEL_SIZE-1)*DILATION
#define NTOK  73        // TT + HALO
#define XSTR  132       // s_xn row stride in halves (even, 8B-align safe, non-pow2)
#define VSTR  40        // s_val row stride in floats (16B-align safe, non-pow2)
#define EPS   1.1920929e-07f

typedef __attribute__((ext_vector_type(8))) _Float16 f16x8;
typedef __attribute__((ext_vector_type(4))) float f32x4;

// sum over each 16-lane row via DPP rotate-butterfly: pure VALU, no LDS pipe.
// row_ror:N ctrl = 0x120+N. After ror 8,4,2,1 every lane holds the 16-lane sum.
template<int CTRL>
__device__ __forceinline__ float dpp_add(float x) {
    int y = __builtin_amdgcn_update_dpp(0, __float_as_int(x), CTRL, 0xF, 0xF, true);
    return x + __int_as_float(y);
}
__device__ __forceinline__ float redsum16(float x) {
    x = dpp_add<0x128>(x);   // row_ror:8
    x = dpp_add<0x124>(x);   // row_ror:4
    x = dpp_add<0x122>(x);   // row_ror:2
    x = dpp_add<0x121>(x);   // row_ror:1
    return x;
}

__device__ __forceinline__ float fast_rcp(float x) {
    return __builtin_amdgcn_rcpf(x);
}

extern "C" __global__ __launch_bounds__(320, 4)
void engram_fused(const float* __restrict__ emb,   // [16,8192,32]
                  const float* __restrict__ hid,   // [16,8192,4,32]
                  const float* __restrict__ Wv,    // [32,32]
                  const float* __restrict__ bv,    // [32]
                  const float* __restrict__ Wk,    // [4,32,32]
                  const float* __restrict__ bk,    // [4,32]
                  const float* __restrict__ n1w,   // [4,32]
                  const float* __restrict__ n2w,   // [4,32]
                  const float* __restrict__ cnw,   // [4,32]
                  const float* __restrict__ cw,    // [128,1,4]
                  float* __restrict__ out)         // [16,8192,128]
{
    __shared__ __align__(16) __half s_xn[NTOK * XSTR];   // x_norm handoff (f16)
    __shared__ __align__(16) float  s_val[TT * VSTR];    // value rows (32 ch) per out token
    __shared__ float  s_gate[TT * 4];                    // gate for output tokens

    const int tid  = threadIdx.x;
    const int b    = blockIdx.x >> 7;      // 16 batches
    const int tile = blockIdx.x & 127;     // 128 tiles of 64 tokens
    const int t0   = tile * TT;

    const int wv  = tid >> 6;     // 0..4  (MFMA m-tile)
    const int ln  = tid & 63;
    const int l15 = ln & 15;
    const int q   = ln >> 4;      // quad 0..3

    // ---- A fragment straight from global: emb row (t0-9+wv*16+l15), d=q*8..+7 ----
    f16x8 a;
    {
        const int tA = t0 - HALO + wv * 16 + l15;
        float4 f0 = {0.f, 0.f, 0.f, 0.f}, f1 = {0.f, 0.f, 0.f, 0.f};
        if (tA >= 0 && tA < 8192) {
            const float4* p = (const float4*)&emb[((b << 13) + tA) * 32 + q * 8];
            f0 = p[0];
            f1 = p[1];
        }
        a[0] = (_Float16)f0.x; a[1] = (_Float16)f0.y;
        a[2] = (_Float16)f0.z; a[3] = (_Float16)f0.w;
        a[4] = (_Float16)f1.x; a[5] = (_Float16)f1.y;
        a[6] = (_Float16)f1.z; a[7] = (_Float16)f1.w;
    }

    // ---- 10 MFMAs: D[token 16][n 160], n<32 = value, else key (g=(n-32)/32) ----
    f32x4 D[10];
    #pragma unroll
    for (int nt = 0; nt < 10; ++nt) {
        const int n = nt * 16 + l15;
        const float* wrow = (n < 32) ? &Wv[n * 32] : &Wk[(n - 32) * 32];
        float4 w0 = ((const float4*)wrow)[q * 2];
        float4 w1 = ((const float4*)wrow)[q * 2 + 1];
        f16x8 bf;
        bf[0] = (_Float16)w0.x; bf[1] = (_Float16)w0.y;
        bf[2] = (_Float16)w0.z; bf[3] = (_Float16)w0.w;
        bf[4] = (_Float16)w1.x; bf[5] = (_Float16)w1.y;
        bf[6] = (_Float16)w1.z; bf[7] = (_Float16)w1.w;
        const float bias = (n < 32) ? bv[n] : bk[n - 32];
        f32x4 c = {bias, bias, bias, bias};
        D[nt] = __builtin_amdgcn_mfma_f32_16x16x32_f16(a, bf, c, 0, 0, 0);
    }

    // per-lane norm weights for its two column groups (c = h*16 + l15)
    float pn1[4][2], pn2[4][2], pcn[4][2];
    #pragma unroll
    for (int g = 0; g < 4; ++g) {
        #pragma unroll
        for (int h = 0; h < 2; ++h) {
            const int c = h * 16 + l15;
            pn1[g][h] = n1w[g * 32 + c];
            pn2[g][h] = n2w[g * 32 + c];
            pcn[g][h] = cnw[g * 32 + c];
        }
    }

    // ---- norms + gate + x_norm, DPP row reductions, Q loaded per row ----
    const int ibase = wv * 16 + q * 4;   // token row = ibase + r
    #pragma unroll
    for (int r = 0; r < 4; ++r) {
        const int i = ibase + r;                 // 0..79
        const int t = t0 - HALO + i;
        const bool ok = (t >= 0 && t < 8192);

        const float V0 = D[0][r], V1 = D[1][r];
        float msv = redsum16(V0 * V0 + V1 * V1) * (1.f / 32.f);
        float gs[4];
        float xn[4][2];
        #pragma unroll
        for (int g = 0; g < 4; ++g) {
            float q0 = 0.f, q1 = 0.f;
            if (ok) {
                const float* qp = &hid[(((b << 13) + t) * 4 + g) * 32 + l15];
                q0 = qp[0];
                q1 = qp[16];
            }
            const float K0 = D[2 + g * 2 + 0][r], K1 = D[2 + g * 2 + 1][r];
            float msk = redsum16(K0 * K0 + K1 * K1) * (1.f / 32.f);
            float rk = rsqrtf(msk + EPS);
            float msq = redsum16(q0 * q0 + q1 * q1) * (1.f / 32.f);
            float rq = rsqrtf(msq + EPS);
            float nk0 = K0 * rk * pn1[g][0], nk1 = K1 * rk * pn1[g][1];
            float nq0 = q0 * rq * pn2[g][0], nq1 = q1 * rq * pn2[g][1];
            float dot = redsum16(nk0 * nq0 + nk1 * nq1) * 0.17677669529663689f; // /sqrt(32)
            float sa = sqrtf(fmaxf(fabsf(dot), 1e-6f));
            float gate = fast_rcp(1.f + __expf(-copysignf(sa, dot)));
            gs[g] = gate;
            float inv = rsqrtf(gate * gate * msv + EPS);
            float sc = gate * inv;
            xn[g][0] = sc * V0 * pcn[g][0];
            xn[g][1] = sc * V1 * pcn[g][1];
        }
        if (i < NTOK) {
            // causal zero-pad: conv input is literally zero for t<0.
            const float tval = (t >= 0) ? 1.f : 0.f;
            #pragma unroll
            for (int g = 0; g < 4; ++g) {
                s_xn[i * XSTR + g * 32 + 0  + l15] = __float2half(tval * xn[g][0]);
                s_xn[i * XSTR + g * 32 + 16 + l15] = __float2half(tval * xn[g][1]);
            }
            if (i >= HALO) {
                const int j = i - HALO;
                s_val[j * VSTR + 0  + l15] = V0;
                s_val[j * VSTR + 16 + l15] = V1;
                if (l15 < 4) {
                    float gsel = (l15 == 0) ? gs[0] : (l15 == 1) ? gs[1]
                               : (l15 == 2) ? gs[2] : gs[3];
                    s_gate[j * 4 + l15] = gsel;
                }
            }
        }
    }
    __syncthreads();

    // ---- phase 2: dilated depthwise conv + SiLU + residual, 4 ch/thread ----
    const float4* cw4p = (const float4*)cw;
    for (int idx = tid; idx < TT * 32; idx += 320) {
        const int j  = idx >> 5;
        const int c4 = (idx & 31) << 2;          // channels c4..c4+3 (same g group)
        float4 w0 = cw4p[c4 + 0];
        float4 w1 = cw4p[c4 + 1];
        float4 w2 = cw4p[c4 + 2];
        float4 w3 = cw4p[c4 + 3];
        float y0 = 0.f, y1 = 0.f, y2 = 0.f, y3 = 0.f;
        #pragma unroll
        for (int k = 0; k < 4; ++k) {
            const __half2* xp = (const __half2*)&s_xn[(j + 3 * k) * XSTR + c4];
            float2 a01 = __half22float2(xp[0]);
            float2 a23 = __half22float2(xp[1]);
            const float wk0 = (k == 0) ? w0.x : (k == 1) ? w0.y : (k == 2) ? w0.z : w0.w;
            const float wk1 = (k == 0) ? w1.x : (k == 1) ? w1.y : (k == 2) ? w1.z : w1.w;
            const float wk2 = (k == 0) ? w2.x : (k == 1) ? w2.y : (k == 2) ? w2.z : w2.w;
            const float wk3 = (k == 0) ? w3.x : (k == 1) ? w3.y : (k == 2) ? w3.z : w3.w;
            y0 = fmaf(a01.x, wk0, y0);
            y1 = fmaf(a01.y, wk1, y1);
            y2 = fmaf(a23.x, wk2, y2);
            y3 = fmaf(a23.y, wk3, y3);
        }
        const float g  = s_gate[j * 4 + (c4 >> 5)];
        // value is broadcast across the 4 groups: index with (c4 & 31), NOT c4.
        // (round-3 bug: c4 up to 124 read past the 32 valid floats per row)
        const f32x4 v  = *(const f32x4*)&s_val[j * VSTR + (c4 & 31)];
        float4 o;
        o.x = g * v[0] + y0 * fast_rcp(1.f + __expf(-y0));
        o.y = g * v[1] + y1 * fast_rcp(1.f + __expf(-y1));
        o.z = g * v[2] + y2 * fast_rcp(1.f + __expf(-y2));
        o.w = g * v[3] + y3 * fast_rcp(1.f + __expf(-y3));
        *(float4*)&out[((b << 13) + t0 + j) * 128 + c4] = o;
    }
}

extern "C" void kernel_launch(void* const* d_in, const int* in_sizes, int n_in,
                              void* d_out, int out_size, void* d_ws, size_t ws_size,
                              hipStream_t stream) {
    const float* emb = (const float*)d_in[0];
    const float* hid = (const float*)d_in[1];
    const float* Wv  = (const float*)d_in[2];
    const float* bvp = (const float*)d_in[3];
    const float* Wk  = (const float*)d_in[4];
    const float* bkp = (const float*)d_in[5];
    const float* n1  = (const float*)d_in[6];
    const float* n2  = (const float*)d_in[7];
    const float* cn  = (const float*)d_in[8];
    const float* cwp = (const float*)d_in[9];
    float* out = (float*)d_out;

    dim3 grid(16 * 128);   // b * (8192/64)
    dim3 block(320);       // 5 waves = 5 MFMA m-tiles
    engram_fused<<<grid, block, 0, stream>>>(emb, hid, Wv, bvp, Wk, bkp, n1, n2, cn, cwp, out);
}

// Round 5
// 191.962 us; speedup vs baseline: 1.2033x; 1.2033x over previous
//
#include <hip/hip_runtime.h>
#include <hip/hip_fp16.h>

#define TT    64        // output tokens per block
#define HALO  9         // (KERNEL_SIZE-1)*DILATION
#define NTOK  73        // TT + HALO
#define XSTR  132       // s_xn row stride in halves (even, non-pow2)
#define VSTR  36        // s_val row stride in floats (16B-aligned rows, non-pow2)
#define EPS   1.1920929e-07f

typedef __attribute__((ext_vector_type(8))) _Float16 f16x8;
typedef __attribute__((ext_vector_type(4))) float f32x4;

// sum over each 16-lane row via DPP rotate-butterfly: pure VALU, no LDS pipe.
template<int CTRL>
__device__ __forceinline__ float dpp_add(float x) {
    int y = __builtin_amdgcn_update_dpp(0, __float_as_int(x), CTRL, 0xF, 0xF, true);
    return x + __int_as_float(y);
}
__device__ __forceinline__ float redsum16(float x) {
    x = dpp_add<0x128>(x);   // row_ror:8
    x = dpp_add<0x124>(x);   // row_ror:4
    x = dpp_add<0x122>(x);   // row_ror:2
    x = dpp_add<0x121>(x);   // row_ror:1
    return x;
}

__device__ __forceinline__ float fast_rcp(float x) {
    return __builtin_amdgcn_rcpf(x);
}

extern "C" __global__ __launch_bounds__(320, 3)
void engram_fused(const float* __restrict__ emb,   // [16,8192,32]
                  const float* __restrict__ hid,   // [16,8192,4,32]
                  const float* __restrict__ Wv,    // [32,32]
                  const float* __restrict__ bv,    // [32]
                  const float* __restrict__ Wk,    // [4,32,32]
                  const float* __restrict__ bk,    // [4,32]
                  const float* __restrict__ n1w,   // [4,32]
                  const float* __restrict__ n2w,   // [4,32]
                  const float* __restrict__ cnw,   // [4,32]
                  const float* __restrict__ cw,    // [128,1,4]
                  float* __restrict__ out)         // [16,8192,128]
{
    __shared__ __align__(16) __half s_xn[NTOK * XSTR];   // x_norm handoff (f16)
    __shared__ __align__(16) float  s_val[TT * VSTR];    // value rows (32 ch, natural order)
    __shared__ float  s_gate[TT * 4];

    const int tid  = threadIdx.x;
    const int b    = blockIdx.x >> 7;
    const int tile = blockIdx.x & 127;
    const int t0   = tile * TT;

    const int wv  = tid >> 6;     // 0..4  (MFMA m-tile)
    const int ln  = tid & 63;
    const int l15 = ln & 15;
    const int q   = ln >> 4;
    const int ibase = wv * 16 + q * 4;   // token row = ibase + r

    // ======== phase 0: issue ALL long-latency loads up front (MLP) ========

    // hid stream (64 MB, the big one): 16 independent float2 loads, branchless.
    // Channel pair per lane = (2*l15, 2*l15+1) to match permuted MFMA columns.
    float2 q2[4][4];
    float  okm[4];
    #pragma unroll
    for (int r = 0; r < 4; ++r) {
        int t = t0 - HALO + ibase + r;
        okm[r] = (t >= 0 && t < 8192) ? 1.f : 0.f;
        int tc = t < 0 ? 0 : (t > 8191 ? 8191 : t);
        const float2* qp = (const float2*)&hid[(size_t)((b << 13) + tc) * 128];
        #pragma unroll
        for (int g = 0; g < 4; ++g) q2[r][g] = qp[g * 16 + l15];
    }

    // emb A-fragment: branchless clamp + mask
    float4 f0, f1;
    float amask;
    {
        const int tA = t0 - HALO + wv * 16 + l15;
        amask = (tA >= 0 && tA < 8192) ? 1.f : 0.f;
        const int tAc = tA < 0 ? 0 : (tA > 8191 ? 8191 : tA);
        const float4* p = (const float4*)&emb[(size_t)((b << 13) + tAc) * 32 + q * 8];
        f0 = p[0];
        f1 = p[1];
    }

    // biases + norm weights, float2 per lane (channels 2*l15, 2*l15+1)
    const float2 bv2 = ((const float2*)bv)[l15];
    float2 bk2[4], wn1[4], wn2[4], wcn[4];
    #pragma unroll
    for (int g = 0; g < 4; ++g) {
        bk2[g] = ((const float2*)(bk  + g * 32))[l15];
        wn1[g] = ((const float2*)(n1w + g * 32))[l15];
        wn2[g] = ((const float2*)(n2w + g * 32))[l15];
        wcn[g] = ((const float2*)(cnw + g * 32))[l15];
    }

    // ======== MFMA: 10 tiles, permuted columns ========
    f16x8 a;
    a[0] = (_Float16)(amask * f0.x); a[1] = (_Float16)(amask * f0.y);
    a[2] = (_Float16)(amask * f0.z); a[3] = (_Float16)(amask * f0.w);
    a[4] = (_Float16)(amask * f1.x); a[5] = (_Float16)(amask * f1.y);
    a[6] = (_Float16)(amask * f1.z); a[7] = (_Float16)(amask * f1.w);

    // Tile nt = 2p+e: column l15 <- weight row ch = 2*l15+e of (p==0 ? Wv : Wk[p-1]).
    // So lane's D pair (D[2p],D[2p+1]) = channels (2*l15, 2*l15+1). Natural order.
    f32x4 D[10];
    #pragma unroll
    for (int nt = 0; nt < 10; ++nt) {
        const int e = nt & 1, p = nt >> 1;
        const int ch = 2 * l15 + e;
        const float* wrow = (p == 0) ? &Wv[ch * 32] : &Wk[((p - 1) * 32 + ch) * 32];
        float4 w0 = ((const float4*)wrow)[q * 2];
        float4 w1 = ((const float4*)wrow)[q * 2 + 1];
        f16x8 bf;
        bf[0] = (_Float16)w0.x; bf[1] = (_Float16)w0.y;
        bf[2] = (_Float16)w0.z; bf[3] = (_Float16)w0.w;
        bf[4] = (_Float16)w1.x; bf[5] = (_Float16)w1.y;
        bf[6] = (_Float16)w1.z; bf[7] = (_Float16)w1.w;
        const float bias = (p == 0) ? (e ? bv2.y : bv2.x)
                                    : (e ? bk2[p - 1].y : bk2[p - 1].x);
        f32x4 c = {bias, bias, bias, bias};
        D[nt] = __builtin_amdgcn_mfma_f32_16x16x32_f16(a, bf, c, 0, 0, 0);
    }

    // ======== norms + gate + x_norm: 3 INDEPENDENT reductions per g ========
    #pragma unroll
    for (int r = 0; r < 4; ++r) {
        const int i = ibase + r;
        const float V0 = D[0][r], V1 = D[1][r];
        float msv = redsum16(V0 * V0 + V1 * V1);   // Σ value² over 32 ch
        float gs[4];
        float xn[4][2];
        #pragma unroll
        for (int g = 0; g < 4; ++g) {
            const float K0 = D[2 + 2 * g][r], K1 = D[3 + 2 * g][r];
            const float q0 = q2[r][g].x * okm[r], q1 = q2[r][g].y * okm[r];
            // three independent DPP chains (interleave in the pipe)
            float msk = redsum16(K0 * K0 + K1 * K1);
            float msq = redsum16(q0 * q0 + q1 * q1);
            float dr  = redsum16(K0 * wn1[g].x * q0 * wn2[g].x
                               + K1 * wn1[g].y * q1 * wn2[g].y);
            float rk = rsqrtf(msk * (1.f / 32.f) + EPS);
            float rq = rsqrtf(msq * (1.f / 32.f) + EPS);
            float dot = dr * rk * rq * 0.17677669529663689f;   // /sqrt(32)
            float sa = sqrtf(fmaxf(fabsf(dot), 1e-6f));
            float gate = fast_rcp(1.f + __expf(-copysignf(sa, dot)));
            gs[g] = gate;
            float sc = gate * rsqrtf(gate * gate * msv * (1.f / 32.f) + EPS);
            xn[g][0] = sc * V0 * wcn[g].x;
            xn[g][1] = sc * V1 * wcn[g].y;
        }
        if (i < NTOK) {
            // causal zero-pad: conv input is literally zero for t<0 (okm[r]==0 there)
            #pragma unroll
            for (int g = 0; g < 4; ++g) {
                __half2 h2 = __floats2half2_rn(okm[r] * xn[g][0], okm[r] * xn[g][1]);
                *(__half2*)&s_xn[i * XSTR + g * 32 + 2 * l15] = h2;
            }
            if (i >= HALO) {
                const int j = i - HALO;
                *(float2*)&s_val[j * VSTR + 2 * l15] = make_float2(V0, V1);
                if (l15 < 4) {
                    float gsel = (l15 == 0) ? gs[0] : (l15 == 1) ? gs[1]
                               : (l15 == 2) ? gs[2] : gs[3];
                    s_gate[j * 4 + l15] = gsel;
                }
            }
        }
    }
    __syncthreads();

    // ======== phase 2: dilated depthwise conv + SiLU + residual ========
    const float4* cw4p = (const float4*)cw;
    for (int idx = tid; idx < TT * 32; idx += 320) {
        const int j  = idx >> 5;
        const int c4 = (idx & 31) << 2;          // channels c4..c4+3
        float4 w0 = cw4p[c4 + 0];
        float4 w1 = cw4p[c4 + 1];
        float4 w2 = cw4p[c4 + 2];
        float4 w3 = cw4p[c4 + 3];
        float y0 = 0.f, y1 = 0.f, y2 = 0.f, y3 = 0.f;
        #pragma unroll
        for (int k = 0; k < 4; ++k) {
            const __half2* xp = (const __half2*)&s_xn[(j + 3 * k) * XSTR + c4];
            float2 a01 = __half22float2(xp[0]);
            float2 a23 = __half22float2(xp[1]);
            const float wk0 = (k == 0) ? w0.x : (k == 1) ? w0.y : (k == 2) ? w0.z : w0.w;
            const float wk1 = (k == 0) ? w1.x : (k == 1) ? w1.y : (k == 2) ? w1.z : w1.w;
            const float wk2 = (k == 0) ? w2.x : (k == 1) ? w2.y : (k == 2) ? w2.z : w2.w;
            const float wk3 = (k == 0) ? w3.x : (k == 1) ? w3.y : (k == 2) ? w3.z : w3.w;
            y0 = fmaf(a01.x, wk0, y0);
            y1 = fmaf(a01.y, wk1, y1);
            y2 = fmaf(a23.x, wk2, y2);
            y3 = fmaf(a23.y, wk3, y3);
        }
        const float g  = s_gate[j * 4 + (c4 >> 5)];
        // value broadcast across groups: index (c4 & 31)
        const f32x4 v  = *(const f32x4*)&s_val[j * VSTR + (c4 & 31)];
        float4 o;
        o.x = g * v[0] + y0 * fast_rcp(1.f + __expf(-y0));
        o.y = g * v[1] + y1 * fast_rcp(1.f + __expf(-y1));
        o.z = g * v[2] + y2 * fast_rcp(1.f + __expf(-y2));
        o.w = g * v[3] + y3 * fast_rcp(1.f + __expf(-y3));
        *(float4*)&out[(size_t)((b << 13) + t0 + j) * 128 + c4] = o;
    }
}

extern "C" void kernel_launch(void* const* d_in, const int* in_sizes, int n_in,
                              void* d_out, int out_size, void* d_ws, size_t ws_size,
                              hipStream_t stream) {
    const float* emb = (const float*)d_in[0];
    const float* hid = (const float*)d_in[1];
    const float* Wv  = (const float*)d_in[2];
    const float* bvp = (const float*)d_in[3];
    const float* Wk  = (const float*)d_in[4];
    const float* bkp = (const float*)d_in[5];
    const float* n1  = (const float*)d_in[6];
    const float* n2  = (const float*)d_in[7];
    const float* cn  = (const float*)d_in[8];
    const float* cwp = (const float*)d_in[9];
    float* out = (float*)d_out;

    dim3 grid(16 * 128);   // b * (8192/64)
    dim3 block(320);       // 5 waves = 5 MFMA m-tiles
    engram_fused<<<grid, block, 0, stream>>>(emb, hid, Wv, bvp, Wk, bkp, n1, n2, cn, cwp, out);
}